// Round 6
// baseline (1280.007 us; speedup 1.0000x reference)
//
#include <hip/hip_runtime.h>
#include <hip/hip_bf16.h>

#define E_ 8
#define H_ 2048
#define D_ 4096
#define R_ 8
#define T_ 2048
#define TWO_D_ 8192
#define SCALE_ 2.0f

typedef __attribute__((ext_vector_type(8))) short short8;
typedef __attribute__((ext_vector_type(4))) float f32x4;

__device__ __forceinline__ unsigned short f2bf(float f) {
  union { float f; unsigned u; } c; c.f = f;
  unsigned u = c.u + 0x7fffu + ((c.u >> 16) & 1u);  // RNE
  return (unsigned short)(u >> 16);
}
__device__ __forceinline__ float bf2f(unsigned short s) {
  union { unsigned u; float f; } c; c.u = ((unsigned)s) << 16;
  return c.f;
}

// async 16B global -> LDS (linear dest: wave-uniform base + lane*16)
__device__ __forceinline__ void gl16(const void* g, void* l) {
  __builtin_amdgcn_global_load_lds(
      (const __attribute__((address_space(1))) void*)g,
      (__attribute__((address_space(3))) void*)l, 16, 0, 0);
}

// LDS byte offset inside a 32KB operand region laid out [qtr][half][32 rows][64 cols bf16]
__device__ __forceinline__ int lds_off(int rr, int ks, int lq) {
  return (((rr >> 5) & 3) << 13) | (((rr >> 7) & 1) << 12) | ((rr & 31) << 7) | (ks << 6) | (lq << 4);
}

// ---------------- rank-8 projection (+ optional bf16 copy of input)
template <int K, bool XBF16, bool WRITEXB>
__global__ __launch_bounds__(256) void k_low(const void* __restrict__ Xv,
                                             const float* __restrict__ A,
                                             float* __restrict__ low,
                                             unsigned short* __restrict__ xbout) {
  int wave = (blockIdx.x * 256 + threadIdx.x) >> 6;
  int lane = threadIdx.x & 63;
  int e = wave >> 11;  // / T_
  const float* Ae = A + (long)e * R_ * K;
  float acc[R_] = {0.f,0.f,0.f,0.f,0.f,0.f,0.f,0.f};
  for (int it = 0; it < K / 256; ++it) {
    int i = it * 256 + lane * 4;
    float xv[4];
    if constexpr (!XBF16) {
      const float* x = (const float*)Xv + (long)wave * K;
      f32x4 v = *(const f32x4*)(x + i);
      xv[0]=v[0]; xv[1]=v[1]; xv[2]=v[2]; xv[3]=v[3];
      if constexpr (WRITEXB) {
        ushort4 u; u.x=f2bf(xv[0]); u.y=f2bf(xv[1]); u.z=f2bf(xv[2]); u.w=f2bf(xv[3]);
        *(ushort4*)(xbout + (long)wave * K + i) = u;
      }
    } else {
      const unsigned short* x = (const unsigned short*)Xv + (long)wave * K;
      ushort4 u = *(const ushort4*)(x + i);
      xv[0]=bf2f(u.x); xv[1]=bf2f(u.y); xv[2]=bf2f(u.z); xv[3]=bf2f(u.w);
    }
    #pragma unroll
    for (int r = 0; r < R_; ++r) {
      f32x4 a = *(const f32x4*)(Ae + r * K + i);
      acc[r] += xv[0]*a[0] + xv[1]*a[1] + xv[2]*a[2] + xv[3]*a[3];
    }
  }
  #pragma unroll
  for (int r = 0; r < R_; ++r) {
    float v = acc[r];
    #pragma unroll
    for (int off = 32; off > 0; off >>= 1) v += __shfl_xor(v, off);
    acc[r] = v;
  }
  if (lane == 0) {
    #pragma unroll
    for (int r = 0; r < R_; ++r) low[(long)wave * R_ + r] = acc[r];
  }
}

// convert one in-flight fp32 B-unit to bf16 and ds_write to its swizzled slot
#define CVT_WR(S0, S1, DST)                                                         \
  { uint4 wv;                                                                       \
    asm("v_cvt_pk_bf16_f32 %0, %1, %2" : "=v"(wv.x) : "v"((S0)[0]), "v"((S0)[1]));  \
    asm("v_cvt_pk_bf16_f32 %0, %1, %2" : "=v"(wv.y) : "v"((S0)[2]), "v"((S0)[3]));  \
    asm("v_cvt_pk_bf16_f32 %0, %1, %2" : "=v"(wv.z) : "v"((S1)[0]), "v"((S1)[1]));  \
    asm("v_cvt_pk_bf16_f32 %0, %1, %2" : "=v"(wv.w) : "v"((S1)[2]), "v"((S1)[3]));  \
    *(uint4*)(DST) = wv; }

// ======================= GEMM1: 256x128(gate)+128(up), BK=64, 8-phase =======================
// h = up*silu(gate); gate_up = x@Wgu^T + SCALE*low1@Bgu^T
// A (tokens) staged bf16 via global_load_lds; B (weights) staged fp32->bf16 in-loop.
__global__ __launch_bounds__(512, 2) void k_gemm1_8p(
    const unsigned short* __restrict__ Xb, const float* __restrict__ Wgu,
    const float* __restrict__ Bgu, const float* __restrict__ low,
    unsigned short* __restrict__ Hout) {
  __shared__ __align__(16) char lds[131072];  // A: d*32768, B: 65536 + d*32768

  const int MT = T_ / 256, NT = D_ / 128;  // 8, 32
  int b = blockIdx.x;
  int cpx = (int)gridDim.x >> 3;
  int swz = (b & 7) * cpx + (b >> 3);
  int e  = swz / (MT * NT);
  int r0 = swz % (MT * NT);
  int nt = r0 / MT, mt = r0 % MT;

  int tid = threadIdx.x, lane = tid & 63;
  int wid = tid >> 6, wm = wid >> 2, wn = wid & 3;
  int lrow = lane & 15, lq = lane >> 4;
  int X4 = (lrow & 7) << 4;
  const int NKT = H_ / 64;  // 32

  unsigned ro = (unsigned)tid * 16;
  unsigned so = ro ^ (((ro >> 7) & 7u) << 4);
  int sh = (so >> 12) & 1, sr = (so >> 7) & 31, sc = (so & 127) >> 1;
  const unsigned short* pA[4]; const float* pB[4];
  #pragma unroll
  for (int q = 0; q < 4; ++q) {
    long arow = (long)e * T_ + mt * 256 + sh * 128 + q * 32 + sr;
    pA[q] = Xb + arow * H_ + sc;
    long wrow = sh ? ((long)e * TWO_D_ + D_ + nt * 128 + q * 32 + sr)
                   : ((long)e * TWO_D_ +      nt * 128 + q * 32 + sr);
    pB[q] = Wgu + wrow * (long)H_ + sc;
  }
  auto SA = [&](int d, int q) { gl16(pA[q], lds + d * 32768 + q * 8192 + ro); pA[q] += 64; };

  f32x4 bl[4][2];  // 4 rotating in-flight B units (static-indexed)
#define G1_IB(s, q) { bl[s][0] = *(const f32x4*)(pB[q]); bl[s][1] = *(const f32x4*)(pB[q] + 4); pB[q] += 64; }
#define G1_WRB(s, dd, qq) CVT_WR(bl[s][0], bl[s][1], lds + 65536 + (dd) * 32768 + (qq) * 8192 + ro)

  f32x4 accg[2][8] = {}, accu[2][8] = {};  // [nj][mi]
  short8 BG[2][2], BU[2][2], af[2][2];

  // ---- prologue: tile0 units 0-3, tile1 units 0-2 (unit (1,3) handled by loop t0.ph0)
  {
    f32x4 pr[7][2];
    #pragma unroll
    for (int q = 0; q < 4; ++q) {
      pr[q][0] = *(const f32x4*)(pB[q]); pr[q][1] = *(const f32x4*)(pB[q] + 4); pB[q] += 64;
      SA(0, q);
    }
    #pragma unroll
    for (int q = 0; q < 3; ++q) {
      pr[4 + q][0] = *(const f32x4*)(pB[q]); pr[4 + q][1] = *(const f32x4*)(pB[q] + 4); pB[q] += 64;
      SA(1, q);
    }
    #pragma unroll
    for (int i = 0; i < 7; ++i) {
      int dd = (i < 4) ? 0 : 1, qq = (i < 4) ? i : i - 4;
      CVT_WR(pr[i][0], pr[i][1], lds + 65536 + dd * 32768 + qq * 8192 + ro);
    }
  }
  asm volatile("s_waitcnt vmcnt(0)" ::: "memory");
  __builtin_amdgcn_s_barrier();

  int rbA = wm * 128 + lrow;
  for (int t = 0; t < NKT; ++t) {
    int d = t & 1;
    const char* Ab = lds + d * 32768;
    const char* Bb = lds + 65536 + d * 32768;

#define G1_MFMA(q)                                                                   \
    __builtin_amdgcn_s_setprio(1);                                                   \
    _Pragma("unroll") for (int m2 = 0; m2 < 2; ++m2)                                 \
      _Pragma("unroll") for (int ks = 0; ks < 2; ++ks)                               \
        _Pragma("unroll") for (int nj = 0; nj < 2; ++nj) {                           \
          accg[nj][(q)*2+m2] = __builtin_amdgcn_mfma_f32_16x16x32_bf16(              \
              BG[nj][ks], af[m2][ks], accg[nj][(q)*2+m2], 0, 0, 0);                  \
          accu[nj][(q)*2+m2] = __builtin_amdgcn_mfma_f32_16x16x32_bf16(              \
              BU[nj][ks], af[m2][ks], accu[nj][(q)*2+m2], 0, 0, 0);                  \
        }                                                                            \
    __builtin_amdgcn_s_setprio(0);

#define G1_LDA(q)                                                                    \
    _Pragma("unroll") for (int m2 = 0; m2 < 2; ++m2)                                 \
      _Pragma("unroll") for (int ks = 0; ks < 2; ++ks)                               \
        af[m2][ks] = *(const short8*)(Ab + (lds_off(rbA + ((q)*2+m2)*16, ks, lq) ^ X4));

#define G1_SYNC()                                                                    \
    __builtin_amdgcn_s_barrier();                                                    \
    asm volatile("s_waitcnt lgkmcnt(0)" ::: "memory");                               \
    __builtin_amdgcn_sched_barrier(0);

    // phase 0
    if (t > 0 && t + 1 < NKT) { G1_WRB(1, d ^ 1, 0); }
    if (t + 1 < NKT) { G1_IB(0, 3); SA(d ^ 1, 3); }
    #pragma unroll
    for (int nj = 0; nj < 2; ++nj)
      #pragma unroll
      for (int ks = 0; ks < 2; ++ks) {
        int rg = wn * 32 + nj * 16 + lrow;
        BG[nj][ks] = *(const short8*)(Bb + (lds_off(rg, ks, lq) ^ X4));
        BU[nj][ks] = *(const short8*)(Bb + (lds_off(rg + 128, ks, lq) ^ X4));
      }
    G1_LDA(0);
    G1_SYNC();
    G1_MFMA(0);
    __builtin_amdgcn_s_barrier();
    // phase 1
    if (t > 0 && t + 1 < NKT) { G1_WRB(2, d ^ 1, 1); }
    if (t + 2 < NKT) { G1_IB(1, 0); SA(d, 0); }
    G1_LDA(1);
    G1_SYNC();
    G1_MFMA(1);
    __builtin_amdgcn_s_barrier();
    // phase 2
    if (t > 0 && t + 1 < NKT) { G1_WRB(3, d ^ 1, 2); }
    if (t + 2 < NKT) { G1_IB(2, 1); SA(d, 1); }
    G1_LDA(2);
    G1_SYNC();
    G1_MFMA(2);
    __builtin_amdgcn_s_barrier();
    // phase 3 (counted vmcnt: 3 slots x 3 VMEM ops in flight)
    if (t + 1 < NKT) { G1_WRB(0, d ^ 1, 3); }
    if (t + 2 < NKT) {
      G1_IB(3, 2); SA(d, 2);
      asm volatile("s_waitcnt vmcnt(9)" ::: "memory");
    } else {
      asm volatile("s_waitcnt vmcnt(0)" ::: "memory");
    }
    G1_LDA(3);
    G1_SYNC();
    G1_MFMA(3);
    __builtin_amdgcn_s_barrier();
  }

  // ---- epilogue: fold LoRA via one rank-8 (K=32 zero-padded) MFMA step
  __syncthreads();
  unsigned short* sLo2 = (unsigned short*)lds;            // [256][32] bf16: SCALE*low1
  unsigned short* sB2  = (unsigned short*)(lds + 16384);  // [256][32] bf16: Bgu rows (gate|up)
  {
    short8 z = {};
    if (tid < 256) {
      const float* lp = low + ((long)e * T_ + mt * 256 + tid) * R_;
      short8 v;
      #pragma unroll
      for (int r = 0; r < 8; ++r) ((unsigned short*)&v)[r] = f2bf(SCALE_ * lp[r]);
      *(short8*)(sLo2 + tid * 32) = v;
      *(short8*)(sLo2 + tid * 32 + 8) = z;
      *(short8*)(sLo2 + tid * 32 + 16) = z;
      *(short8*)(sLo2 + tid * 32 + 24) = z;
    } else {
      int r = tid - 256;
      long wrow = (r < 128) ? ((long)e * TWO_D_ + nt * 128 + r)
                            : ((long)e * TWO_D_ + D_ + nt * 128 + (r - 128));
      const float* bp = Bgu + wrow * R_;
      short8 v;
      #pragma unroll
      for (int k = 0; k < 8; ++k) ((unsigned short*)&v)[k] = f2bf(bp[k]);
      *(short8*)(sB2 + r * 32) = v;
      *(short8*)(sB2 + r * 32 + 8) = z;
      *(short8*)(sB2 + r * 32 + 16) = z;
      *(short8*)(sB2 + r * 32 + 24) = z;
    }
  }
  __syncthreads();
  {
    #pragma unroll
    for (int mi = 0; mi < 8; ++mi) {
      short8 alo = *(const short8*)(sLo2 + (rbA + mi * 16) * 32 + lq * 8);
      #pragma unroll
      for (int nj = 0; nj < 2; ++nj) {
        int rg = wn * 32 + nj * 16 + lrow;
        short8 bg2 = *(const short8*)(sB2 + rg * 32 + lq * 8);
        short8 bu2 = *(const short8*)(sB2 + (rg + 128) * 32 + lq * 8);
        accg[nj][mi] = __builtin_amdgcn_mfma_f32_16x16x32_bf16(bg2, alo, accg[nj][mi], 0, 0, 0);
        accu[nj][mi] = __builtin_amdgcn_mfma_f32_16x16x32_bf16(bu2, alo, accu[nj][mi], 0, 0, 0);
      }
    }
  }
  // silu + pack -> sT [256][136], then coalesced store
  unsigned short* sT = (unsigned short*)(lds + 32768);
  #pragma unroll
  for (int mi = 0; mi < 8; ++mi) {
    int tl = rbA + mi * 16;
    #pragma unroll
    for (int nj = 0; nj < 2; ++nj) {
      int cb = wn * 32 + nj * 16 + lq * 4;
      ushort4 o;
      #pragma unroll
      for (int j = 0; j < 4; ++j) {
        float gate = accg[nj][mi][j];
        float up   = accu[nj][mi][j];
        float hh = up * (gate / (1.f + __expf(-gate)));
        (&o.x)[j] = f2bf(hh);
      }
      *(ushort4*)(sT + tl * 136 + cb) = o;
    }
  }
  __syncthreads();
  {
    long base = ((long)e * T_ + mt * 256) * D_ + nt * 128;
    int rr2 = tid >> 4, cc2 = (tid & 15) * 8;
    #pragma unroll
    for (int p = 0; p < 8; ++p) {
      int r = p * 32 + rr2;
      short8 v = *(const short8*)(sT + r * 136 + cc2);
      *(short8*)(Hout + base + (long)r * D_ + cc2) = v;
    }
  }
}

// ======================= GEMM2: 256x256, BK=64, 8-phase =======================
// out = h@Wd^T + SCALE*low2@Bd^T (fp32 out; Wd staged fp32->bf16 in-loop)
__global__ __launch_bounds__(512, 2) void k_gemm2_8p(
    const unsigned short* __restrict__ Hin, const float* __restrict__ Wd,
    const float* __restrict__ Bd, const float* __restrict__ low,
    float* __restrict__ Out) {
  __shared__ __align__(16) char lds[131072];

  const int MT = T_ / 256, NT = H_ / 256;  // 8, 8
  int b = blockIdx.x;
  int cpx = (int)gridDim.x >> 3;
  int swz = (b & 7) * cpx + (b >> 3);
  int e  = swz / (MT * NT);
  int r0 = swz % (MT * NT);
  int nt = r0 / MT, mt = r0 % MT;

  int tid = threadIdx.x, lane = tid & 63;
  int wid = tid >> 6, wm = wid >> 2, wn = wid & 3;
  int lrow = lane & 15, lq = lane >> 4;
  int X4 = (lrow & 7) << 4;
  const int NKT = D_ / 64;  // 64

  unsigned ro = (unsigned)tid * 16;
  unsigned so = ro ^ (((ro >> 7) & 7u) << 4);
  int sh = (so >> 12) & 1, sr = (so >> 7) & 31, sc = (so & 127) >> 1;
  const unsigned short* pA[4]; const float* pB[4];
  #pragma unroll
  for (int q = 0; q < 4; ++q) {
    long arow = (long)e * T_ + mt * 256 + sh * 128 + q * 32 + sr;
    pA[q] = Hin + arow * D_ + sc;
    long wrow = (long)e * H_ + nt * 256 + sh * 128 + q * 32 + sr;
    pB[q] = Wd + wrow * (long)D_ + sc;
  }
  auto SA = [&](int d, int q) { gl16(pA[q], lds + d * 32768 + q * 8192 + ro); pA[q] += 64; };

  f32x4 bl[4][2];
#define G2_IB(s, q) { bl[s][0] = *(const f32x4*)(pB[q]); bl[s][1] = *(const f32x4*)(pB[q] + 4); pB[q] += 64; }
#define G2_WRB(s, dd, qq) CVT_WR(bl[s][0], bl[s][1], lds + 65536 + (dd) * 32768 + (qq) * 8192 + ro)

  f32x4 acc[8][4] = {};  // [mi][ni]
  short8 BF[4][2], af[2][2];

  {
    f32x4 pr[7][2];
    #pragma unroll
    for (int q = 0; q < 4; ++q) {
      pr[q][0] = *(const f32x4*)(pB[q]); pr[q][1] = *(const f32x4*)(pB[q] + 4); pB[q] += 64;
      SA(0, q);
    }
    #pragma unroll
    for (int q = 0; q < 3; ++q) {
      pr[4 + q][0] = *(const f32x4*)(pB[q]); pr[4 + q][1] = *(const f32x4*)(pB[q] + 4); pB[q] += 64;
      SA(1, q);
    }
    #pragma unroll
    for (int i = 0; i < 7; ++i) {
      int dd = (i < 4) ? 0 : 1, qq = (i < 4) ? i : i - 4;
      CVT_WR(pr[i][0], pr[i][1], lds + 65536 + dd * 32768 + qq * 8192 + ro);
    }
  }
  asm volatile("s_waitcnt vmcnt(0)" ::: "memory");
  __builtin_amdgcn_s_barrier();

  int rbA = wm * 128 + lrow;
  for (int t = 0; t < NKT; ++t) {
    int d = t & 1;
    const char* Ab = lds + d * 32768;
    const char* Bb = lds + 65536 + d * 32768;

#define G2_MFMA(q)                                                                   \
    __builtin_amdgcn_s_setprio(1);                                                   \
    _Pragma("unroll") for (int m2 = 0; m2 < 2; ++m2)                                 \
      _Pragma("unroll") for (int ks = 0; ks < 2; ++ks)                               \
        _Pragma("unroll") for (int ni = 0; ni < 4; ++ni)                             \
          acc[(q)*2+m2][ni] = __builtin_amdgcn_mfma_f32_16x16x32_bf16(               \
              af[m2][ks], BF[ni][ks], acc[(q)*2+m2][ni], 0, 0, 0);                   \
    __builtin_amdgcn_s_setprio(0);

#define G2_LDA(q)                                                                    \
    _Pragma("unroll") for (int m2 = 0; m2 < 2; ++m2)                                 \
      _Pragma("unroll") for (int ks = 0; ks < 2; ++ks)                               \
        af[m2][ks] = *(const short8*)(Ab + (lds_off(rbA + ((q)*2+m2)*16, ks, lq) ^ X4));

#define G2_SYNC()                                                                    \
    __builtin_amdgcn_s_barrier();                                                    \
    asm volatile("s_waitcnt lgkmcnt(0)" ::: "memory");                               \
    __builtin_amdgcn_sched_barrier(0);

    // phase 0
    if (t > 0 && t + 1 < NKT) { G2_WRB(1, d ^ 1, 0); }
    if (t + 1 < NKT) { G2_IB(0, 3); SA(d ^ 1, 3); }
    #pragma unroll
    for (int ni = 0; ni < 4; ++ni)
      #pragma unroll
      for (int ks = 0; ks < 2; ++ks)
        BF[ni][ks] = *(const short8*)(Bb + (lds_off(wn * 64 + ni * 16 + lrow, ks, lq) ^ X4));
    G2_LDA(0);
    G2_SYNC();
    G2_MFMA(0);
    __builtin_amdgcn_s_barrier();
    // phase 1
    if (t > 0 && t + 1 < NKT) { G2_WRB(2, d ^ 1, 1); }
    if (t + 2 < NKT) { G2_IB(1, 0); SA(d, 0); }
    G2_LDA(1);
    G2_SYNC();
    G2_MFMA(1);
    __builtin_amdgcn_s_barrier();
    // phase 2
    if (t > 0 && t + 1 < NKT) { G2_WRB(3, d ^ 1, 2); }
    if (t + 2 < NKT) { G2_IB(2, 1); SA(d, 1); }
    G2_LDA(2);
    G2_SYNC();
    G2_MFMA(2);
    __builtin_amdgcn_s_barrier();
    // phase 3
    if (t + 1 < NKT) { G2_WRB(0, d ^ 1, 3); }
    if (t + 2 < NKT) {
      G2_IB(3, 2); SA(d, 2);
      asm volatile("s_waitcnt vmcnt(9)" ::: "memory");
    } else {
      asm volatile("s_waitcnt vmcnt(0)" ::: "memory");
    }
    G2_LDA(3);
    G2_SYNC();
    G2_MFMA(3);
    __builtin_amdgcn_s_barrier();
  }

  // ---- epilogue: LoRA via rank-8 MFMA, direct (row-major) stores
  __syncthreads();
  unsigned short* sLo2 = (unsigned short*)lds;            // [256][32] SCALE*low2
  unsigned short* sB2  = (unsigned short*)(lds + 16384);  // [256][32] Bd rows
  {
    short8 z = {};
    if (tid < 256) {
      const float* lp = low + ((long)e * T_ + mt * 256 + tid) * R_;
      short8 v;
      #pragma unroll
      for (int r = 0; r < 8; ++r) ((unsigned short*)&v)[r] = f2bf(SCALE_ * lp[r]);
      *(short8*)(sLo2 + tid * 32) = v;
      *(short8*)(sLo2 + tid * 32 + 8) = z;
      *(short8*)(sLo2 + tid * 32 + 16) = z;
      *(short8*)(sLo2 + tid * 32 + 24) = z;
    } else {
      int r = tid - 256;
      const float* bp = Bd + ((long)e * H_ + nt * 256 + r) * R_;
      short8 v;
      #pragma unroll
      for (int k = 0; k < 8; ++k) ((unsigned short*)&v)[k] = f2bf(bp[k]);
      *(short8*)(sB2 + r * 32) = v;
      *(short8*)(sB2 + r * 32 + 8) = z;
      *(short8*)(sB2 + r * 32 + 16) = z;
      *(short8*)(sB2 + r * 32 + 24) = z;
    }
  }
  __syncthreads();
  #pragma unroll
  for (int mi = 0; mi < 8; ++mi) {
    short8 alo = *(const short8*)(sLo2 + (rbA + mi * 16) * 32 + lq * 8);
    #pragma unroll
    for (int ni = 0; ni < 4; ++ni) {
      short8 bd2 = *(const short8*)(sB2 + (wn * 64 + ni * 16 + lrow) * 32 + lq * 8);
      acc[mi][ni] = __builtin_amdgcn_mfma_f32_16x16x32_bf16(alo, bd2, acc[mi][ni], 0, 0, 0);
    }
  }
  {
    long rowbase = (long)e * T_ + mt * 256 + wm * 128;
    int colbase = nt * 256 + wn * 64;
    #pragma unroll
    for (int mi = 0; mi < 8; ++mi)
      #pragma unroll
      for (int j = 0; j < 4; ++j) {
        long row = rowbase + mi * 16 + lq * 4 + j;
        #pragma unroll
        for (int ni = 0; ni < 4; ++ni)
          Out[row * H_ + colbase + ni * 16 + lrow] = acc[mi][ni][j];
      }
  }
}

extern "C" void kernel_launch(void* const* d_in, const int* in_sizes, int n_in,
                              void* d_out, int out_size, void* d_ws, size_t ws_size,
                              hipStream_t stream) {
  const float* x   = (const float*)d_in[0];
  const float* Wgu = (const float*)d_in[1];
  const float* Agu = (const float*)d_in[2];
  const float* Bgu = (const float*)d_in[3];
  const float* Wd  = (const float*)d_in[4];
  const float* Ad  = (const float*)d_in[5];
  const float* Bd  = (const float*)d_in[6];
  float* out = (float*)d_out;

  char* ws = (char*)d_ws;
  const size_t SZ_H   = (size_t)E_ * T_ * D_ * 2;        // 128 MiB bf16 h
  const size_t SZ_LOW = (size_t)E_ * T_ * R_ * 4;        // 512 KiB

  unsigned short* hbuf = (unsigned short*)ws;
  float* low1 = (float*)(ws + SZ_H);
  float* low2 = (float*)(ws + SZ_H + SZ_LOW);
  unsigned short* xb   = (unsigned short*)(ws + SZ_H + 2 * SZ_LOW);

  hipLaunchKernelGGL((k_low<H_, false, true>), dim3(E_ * T_ / 4), dim3(256), 0, stream,
                     (const void*)x, Agu, low1, xb);
  hipLaunchKernelGGL(k_gemm1_8p, dim3(E_ * (T_ / 256) * (D_ / 128)), dim3(512), 0, stream,
                     xb, Wgu, Bgu, low1, hbuf);
  hipLaunchKernelGGL((k_low<D_, true, false>), dim3(E_ * T_ / 4), dim3(256), 0, stream,
                     (const void*)hbuf, Ad, low2, (unsigned short*)nullptr);
  hipLaunchKernelGGL(k_gemm2_8p, dim3(E_ * (T_ / 256) * (H_ / 256)), dim3(512), 0, stream,
                     hbuf, Wd, Bd, low2, out);
}

// Round 7
// 1171.146 us; speedup vs baseline: 1.0930x; 1.0930x over previous
//
#include <hip/hip_runtime.h>
#include <hip/hip_bf16.h>

#define E_ 8
#define H_ 2048
#define D_ 4096
#define R_ 8
#define T_ 2048
#define TWO_D_ 8192
#define SCALE_ 2.0f

typedef __attribute__((ext_vector_type(8))) short short8;
typedef __attribute__((ext_vector_type(4))) float f32x4;

__device__ __forceinline__ unsigned short f2bf(float f) {
  union { float f; unsigned u; } c; c.f = f;
  unsigned u = c.u + 0x7fffu + ((c.u >> 16) & 1u);  // RNE
  return (unsigned short)(u >> 16);
}
__device__ __forceinline__ float bf2f(unsigned short s) {
  union { unsigned u; float f; } c; c.u = ((unsigned)s) << 16;
  return c.f;
}

// async 16B global -> LDS (linear dest: wave-uniform base + lane*16)
__device__ __forceinline__ void gl16(const void* g, void* l) {
  __builtin_amdgcn_global_load_lds(
      (const __attribute__((address_space(1))) void*)g,
      (__attribute__((address_space(3))) void*)l, 16, 0, 0);
}

// LDS byte offset inside a 32KB operand region laid out [qtr][half][32 rows][64 cols bf16]
__device__ __forceinline__ int lds_off(int rr, int ks, int lq) {
  return (((rr >> 5) & 3) << 13) | (((rr >> 7) & 1) << 12) | ((rr & 31) << 7) | (ks << 6) | (lq << 4);
}

// ---------------- combined: low1 = x@Agu^T (+ bf16 copy of x)  ||  Wgu fp32->bf16
__global__ __launch_bounds__(256) void k_pre(const float* __restrict__ x,
                                             const float* __restrict__ Agu,
                                             float* __restrict__ low,
                                             unsigned short* __restrict__ xb,
                                             const float* __restrict__ Wgu,
                                             unsigned short* __restrict__ wgub) {
  const int NB_LOW = E_ * T_ / 4;  // 4096
  if (blockIdx.x < NB_LOW) {
    int wave = (blockIdx.x * 256 + threadIdx.x) >> 6;
    int lane = threadIdx.x & 63;
    int e = wave >> 11;
    const float* Ae = Agu + (long)e * R_ * H_;
    float acc[R_] = {0.f,0.f,0.f,0.f,0.f,0.f,0.f,0.f};
    for (int it = 0; it < H_ / 256; ++it) {
      int i = it * 256 + lane * 4;
      const float* xp = x + (long)wave * H_;
      f32x4 v = *(const f32x4*)(xp + i);
      ushort4 u; u.x=f2bf(v[0]); u.y=f2bf(v[1]); u.z=f2bf(v[2]); u.w=f2bf(v[3]);
      *(ushort4*)(xb + (long)wave * H_ + i) = u;
      #pragma unroll
      for (int r = 0; r < R_; ++r) {
        f32x4 a = *(const f32x4*)(Ae + r * H_ + i);
        acc[r] += v[0]*a[0] + v[1]*a[1] + v[2]*a[2] + v[3]*a[3];
      }
    }
    #pragma unroll
    for (int r = 0; r < R_; ++r) {
      float v = acc[r];
      #pragma unroll
      for (int off = 32; off > 0; off >>= 1) v += __shfl_xor(v, off);
      acc[r] = v;
    }
    if (lane == 0) {
      #pragma unroll
      for (int r = 0; r < R_; ++r) low[(long)wave * R_ + r] = acc[r];
    }
  } else {
    // fp32 -> bf16 of Wgu, grid-stride
    const long n = (long)E_ * TWO_D_ * H_;
    long i = ((long)(blockIdx.x - NB_LOW) * 256 + threadIdx.x) * 8;
    const long stride = (long)1024 * 256 * 8;
    for (; i < n; i += stride) {
      f32x4 a = *(const f32x4*)(Wgu + i);
      f32x4 b = *(const f32x4*)(Wgu + i + 4);
      ushort4 lo, hi;
      lo.x=f2bf(a[0]); lo.y=f2bf(a[1]); lo.z=f2bf(a[2]); lo.w=f2bf(a[3]);
      hi.x=f2bf(b[0]); hi.y=f2bf(b[1]); hi.z=f2bf(b[2]); hi.w=f2bf(b[3]);
      *(ushort4*)(wgub + i) = lo;
      *(ushort4*)(wgub + i + 4) = hi;
    }
  }
}

// ---------------- rank-8 projection from bf16 h (low2)
__global__ __launch_bounds__(256) void k_low2(const unsigned short* __restrict__ Hb,
                                              const float* __restrict__ Ad,
                                              float* __restrict__ low) {
  int wave = (blockIdx.x * 256 + threadIdx.x) >> 6;
  int lane = threadIdx.x & 63;
  int e = wave >> 11;
  const float* Ae = Ad + (long)e * R_ * D_;
  float acc[R_] = {0.f,0.f,0.f,0.f,0.f,0.f,0.f,0.f};
  for (int it = 0; it < D_ / 256; ++it) {
    int i = it * 256 + lane * 4;
    ushort4 u = *(const ushort4*)(Hb + (long)wave * D_ + i);
    float xv[4] = {bf2f(u.x), bf2f(u.y), bf2f(u.z), bf2f(u.w)};
    #pragma unroll
    for (int r = 0; r < R_; ++r) {
      f32x4 a = *(const f32x4*)(Ae + r * D_ + i);
      acc[r] += xv[0]*a[0] + xv[1]*a[1] + xv[2]*a[2] + xv[3]*a[3];
    }
  }
  #pragma unroll
  for (int r = 0; r < R_; ++r) {
    float v = acc[r];
    #pragma unroll
    for (int off = 32; off > 0; off >>= 1) v += __shfl_xor(v, off);
    acc[r] = v;
  }
  if (lane == 0) {
    #pragma unroll
    for (int r = 0; r < R_; ++r) low[(long)wave * R_ + r] = acc[r];
  }
}

// ======================= GEMM1: 256x128(gate)+128(up), BK=64, 8-phase =======================
// h = up*silu(gate); gate_up = x@Wgu^T + SCALE*low1@Bgu^T (LoRA folded as rank-8 MFMA step)
// Rides Wd fp32->bf16 conversion at phase 3 (2-stage pipeline, free under vmcnt(6)).
__global__ __launch_bounds__(512, 2) void k_gemm1_8p(
    const unsigned short* __restrict__ Xb, const unsigned short* __restrict__ Wb,
    const float* __restrict__ Bgu, const float* __restrict__ low,
    unsigned short* __restrict__ Hout,
    const float* __restrict__ WdSrc, unsigned short* __restrict__ WdDst) {
  __shared__ __align__(16) char lds[131072];  // A: d*32768, B: 65536 + d*32768

  const int MT = T_ / 256, NT = D_ / 128;  // 8, 32
  int b = blockIdx.x;
  int cpx = (int)gridDim.x >> 3;
  int swz = (b & 7) * cpx + (b >> 3);     // bijective: grid % 8 == 0
  int e  = swz / (MT * NT);
  int r0 = swz % (MT * NT);
  int nt = r0 / MT, mt = r0 % MT;

  int tid = threadIdx.x, lane = tid & 63;
  int wid = tid >> 6, wm = wid >> 2, wn = wid & 3;
  int lrow = lane & 15, lq = lane >> 4;
  int X4 = (lrow & 7) << 4;
  const int NKT = H_ / 64;  // 32
  const long cid = (long)blockIdx.x * 512 + tid;  // conversion chunk id (4 floats)

  unsigned ro = (unsigned)tid * 16;
  unsigned so = ro ^ (((ro >> 7) & 7u) << 4);
  int sh = (so >> 12) & 1, sr = (so >> 7) & 31, sc = (so & 127) >> 1;
  const unsigned short* pA[4]; const unsigned short* pB[4];
  #pragma unroll
  for (int q = 0; q < 4; ++q) {
    long arow = (long)e * T_ + mt * 256 + sh * 128 + q * 32 + sr;
    pA[q] = Xb + arow * H_ + sc;
    long wrow = sh ? ((long)e * TWO_D_ + D_ + nt * 128 + q * 32 + sr)
                   : ((long)e * TWO_D_ +      nt * 128 + q * 32 + sr);
    pB[q] = Wb + wrow * (long)H_ + sc;
  }
  auto SA = [&](int d, int q) { gl16(pA[q], lds + d * 32768 + q * 8192 + ro); pA[q] += 64; };
  auto SB = [&](int d, int q) { gl16(pB[q], lds + 65536 + d * 32768 + q * 8192 + ro); pB[q] += 64; };

  f32x4 accg[2][8] = {}, accu[2][8] = {};  // [nj][mi]
  short8 BG[2][2], BU[2][2], af[2][2];
  f32x4 cr;  // in-flight Wd conversion chunk

  // ---- prologue: tile0 all 8 units, tile1 first 6 units; wait tile0 complete
  SA(0,0); SB(0,0); SA(0,1); SB(0,1); SA(0,2); SB(0,2); SA(0,3); SB(0,3);
  SA(1,0); SB(1,0); SA(1,1); SB(1,1); SA(1,2); SB(1,2);
  asm volatile("s_waitcnt vmcnt(6)" ::: "memory");
  __builtin_amdgcn_s_barrier();

  int rbA = wm * 128 + lrow;
  for (int t = 0; t < NKT; ++t) {
    int d = t & 1;
    const char* Ab = lds + d * 32768;
    const char* Bb = lds + 65536 + d * 32768;

#define G1_MFMA(q)                                                                   \
    __builtin_amdgcn_s_setprio(1);                                                   \
    _Pragma("unroll") for (int m2 = 0; m2 < 2; ++m2)                                 \
      _Pragma("unroll") for (int ks = 0; ks < 2; ++ks)                               \
        _Pragma("unroll") for (int nj = 0; nj < 2; ++nj) {                           \
          accg[nj][(q)*2+m2] = __builtin_amdgcn_mfma_f32_16x16x32_bf16(              \
              BG[nj][ks], af[m2][ks], accg[nj][(q)*2+m2], 0, 0, 0);                  \
          accu[nj][(q)*2+m2] = __builtin_amdgcn_mfma_f32_16x16x32_bf16(              \
              BU[nj][ks], af[m2][ks], accu[nj][(q)*2+m2], 0, 0, 0);                  \
        }                                                                            \
    __builtin_amdgcn_s_setprio(0);

#define G1_LDA(q)                                                                    \
    _Pragma("unroll") for (int m2 = 0; m2 < 2; ++m2)                                 \
      _Pragma("unroll") for (int ks = 0; ks < 2; ++ks)                               \
        af[m2][ks] = *(const short8*)(Ab + (lds_off(rbA + ((q)*2+m2)*16, ks, lq) ^ X4));

#define G1_SYNC()                                                                    \
    __builtin_amdgcn_s_barrier();                                                    \
    asm volatile("s_waitcnt lgkmcnt(0)" ::: "memory");                               \
    __builtin_amdgcn_sched_barrier(0);

    // phase 0: B-frags + A-quad0; stage tile t+1 last units
    #pragma unroll
    for (int nj = 0; nj < 2; ++nj)
      #pragma unroll
      for (int ks = 0; ks < 2; ++ks) {
        int rg = wn * 32 + nj * 16 + lrow;
        BG[nj][ks] = *(const short8*)(Bb + (lds_off(rg, ks, lq) ^ X4));
        BU[nj][ks] = *(const short8*)(Bb + (lds_off(rg + 128, ks, lq) ^ X4));
      }
    G1_LDA(0);
    if (t + 1 < NKT) { SA(d ^ 1, 3); SB(d ^ 1, 3); }
    G1_SYNC();
    G1_MFMA(0);
    __builtin_amdgcn_s_barrier();
    // phase 1
    G1_LDA(1);
    if (t + 2 < NKT) { SA(d, 0); SB(d, 0); }
    G1_SYNC();
    G1_MFMA(1);
    __builtin_amdgcn_s_barrier();
    // phase 2
    G1_LDA(2);
    if (t + 2 < NKT) { SA(d, 1); SB(d, 1); }
    G1_SYNC();
    G1_MFMA(2);
    __builtin_amdgcn_s_barrier();
    // phase 3 (counted vmcnt: 6 loads of tile t+2 may stay in flight)
    G1_LDA(3);
    if (t + 2 < NKT) {
      SA(d, 2); SB(d, 2);
      asm volatile("s_waitcnt vmcnt(6)" ::: "memory");
    } else {
      asm volatile("s_waitcnt vmcnt(0)" ::: "memory");
    }
    // ---- Wd conversion ride (free: cr's load is >6 VMEM ops old => retired by the wait)
    if (t >= 2 && t <= 17) {
      ushort4 o; o.x = f2bf(cr[0]); o.y = f2bf(cr[1]); o.z = f2bf(cr[2]); o.w = f2bf(cr[3]);
      *(ushort4*)(WdDst + ((long)(t - 2) * 1048576 + cid) * 4) = o;
    }
    if (t >= 1 && t <= 16) {
      cr = *(const f32x4*)(WdSrc + ((long)(t - 1) * 1048576 + cid) * 4);
    }
    G1_SYNC();
    G1_MFMA(3);
    __builtin_amdgcn_s_barrier();
  }

  // ---- epilogue: fold LoRA via one rank-8 (K=32 zero-padded) MFMA step
  __syncthreads();
  unsigned short* sLo2 = (unsigned short*)lds;            // [256][32] bf16: SCALE*low1
  unsigned short* sB2  = (unsigned short*)(lds + 16384);  // [256][32] bf16: Bgu rows (gate|up)
  {
    short8 z = {};
    if (tid < 256) {
      const float* lp = low + ((long)e * T_ + mt * 256 + tid) * R_;
      short8 v;
      #pragma unroll
      for (int r = 0; r < 8; ++r) ((unsigned short*)&v)[r] = f2bf(SCALE_ * lp[r]);
      *(short8*)(sLo2 + tid * 32) = v;
      *(short8*)(sLo2 + tid * 32 + 8) = z;
      *(short8*)(sLo2 + tid * 32 + 16) = z;
      *(short8*)(sLo2 + tid * 32 + 24) = z;
    } else {
      int r = tid - 256;
      long wrow = (r < 128) ? ((long)e * TWO_D_ + nt * 128 + r)
                            : ((long)e * TWO_D_ + D_ + nt * 128 + (r - 128));
      const float* bp = Bgu + wrow * R_;
      short8 v;
      #pragma unroll
      for (int k = 0; k < 8; ++k) ((unsigned short*)&v)[k] = f2bf(bp[k]);
      *(short8*)(sB2 + r * 32) = v;
      *(short8*)(sB2 + r * 32 + 8) = z;
      *(short8*)(sB2 + r * 32 + 16) = z;
      *(short8*)(sB2 + r * 32 + 24) = z;
    }
  }
  __syncthreads();
  {
    #pragma unroll
    for (int mi = 0; mi < 8; ++mi) {
      short8 alo = *(const short8*)(sLo2 + (rbA + mi * 16) * 32 + lq * 8);
      #pragma unroll
      for (int nj = 0; nj < 2; ++nj) {
        int rg = wn * 32 + nj * 16 + lrow;
        short8 bg2 = *(const short8*)(sB2 + rg * 32 + lq * 8);
        short8 bu2 = *(const short8*)(sB2 + (rg + 128) * 32 + lq * 8);
        accg[nj][mi] = __builtin_amdgcn_mfma_f32_16x16x32_bf16(bg2, alo, accg[nj][mi], 0, 0, 0);
        accu[nj][mi] = __builtin_amdgcn_mfma_f32_16x16x32_bf16(bu2, alo, accu[nj][mi], 0, 0, 0);
      }
    }
  }
  // silu + pack -> sT [256][136], then coalesced store
  unsigned short* sT = (unsigned short*)(lds + 32768);
  #pragma unroll
  for (int mi = 0; mi < 8; ++mi) {
    int tl = rbA + mi * 16;
    #pragma unroll
    for (int nj = 0; nj < 2; ++nj) {
      int cb = wn * 32 + nj * 16 + lq * 4;
      ushort4 o;
      #pragma unroll
      for (int j = 0; j < 4; ++j) {
        float gate = accg[nj][mi][j];
        float up   = accu[nj][mi][j];
        float hh = up * (gate / (1.f + __expf(-gate)));
        (&o.x)[j] = f2bf(hh);
      }
      *(ushort4*)(sT + tl * 136 + cb) = o;
    }
  }
  __syncthreads();
  {
    long base = ((long)e * T_ + mt * 256) * D_ + nt * 128;
    int rr2 = tid >> 4, cc2 = (tid & 15) * 8;
    #pragma unroll
    for (int p = 0; p < 8; ++p) {
      int r = p * 32 + rr2;
      short8 v = *(const short8*)(sT + r * 136 + cc2);
      *(short8*)(Hout + base + (long)r * D_ + cc2) = v;
    }
  }
}

// ======================= GEMM2: 256x256, BK=64, 8-phase =======================
// out = h@Wd^T + SCALE*low2@Bd^T (fp32 out; LoRA folded as rank-8 MFMA step)
__global__ __launch_bounds__(512, 2) void k_gemm2_8p(
    const unsigned short* __restrict__ Hin, const unsigned short* __restrict__ Wdb,
    const float* __restrict__ Bd, const float* __restrict__ low,
    float* __restrict__ Out) {
  __shared__ __align__(16) char lds[131072];

  const int MT = T_ / 256, NT = H_ / 256;  // 8, 8
  int b = blockIdx.x;
  int cpx = (int)gridDim.x >> 3;
  int swz = (b & 7) * cpx + (b >> 3);
  int e  = swz / (MT * NT);
  int r0 = swz % (MT * NT);
  int nt = r0 / MT, mt = r0 % MT;

  int tid = threadIdx.x, lane = tid & 63;
  int wid = tid >> 6, wm = wid >> 2, wn = wid & 3;
  int lrow = lane & 15, lq = lane >> 4;
  int X4 = (lrow & 7) << 4;
  const int NKT = D_ / 64;  // 64

  unsigned ro = (unsigned)tid * 16;
  unsigned so = ro ^ (((ro >> 7) & 7u) << 4);
  int sh = (so >> 12) & 1, sr = (so >> 7) & 31, sc = (so & 127) >> 1;
  const unsigned short* pA[4]; const unsigned short* pB[4];
  #pragma unroll
  for (int q = 0; q < 4; ++q) {
    long arow = (long)e * T_ + mt * 256 + sh * 128 + q * 32 + sr;
    pA[q] = Hin + arow * D_ + sc;
    long wrow = (long)e * H_ + nt * 256 + sh * 128 + q * 32 + sr;
    pB[q] = Wdb + wrow * (long)D_ + sc;
  }
  auto SA = [&](int d, int q) { gl16(pA[q], lds + d * 32768 + q * 8192 + ro); pA[q] += 64; };
  auto SB = [&](int d, int q) { gl16(pB[q], lds + 65536 + d * 32768 + q * 8192 + ro); pB[q] += 64; };

  f32x4 acc[8][4] = {};  // [mi][ni]
  short8 BF[4][2], af[2][2];

  SA(0,0); SB(0,0); SA(0,1); SB(0,1); SA(0,2); SB(0,2); SA(0,3); SB(0,3);
  SA(1,0); SB(1,0); SA(1,1); SB(1,1); SA(1,2); SB(1,2);
  asm volatile("s_waitcnt vmcnt(6)" ::: "memory");
  __builtin_amdgcn_s_barrier();

  int rbA = wm * 128 + lrow;
  for (int t = 0; t < NKT; ++t) {
    int d = t & 1;
    const char* Ab = lds + d * 32768;
    const char* Bb = lds + 65536 + d * 32768;

#define G2_MFMA(q)                                                                   \
    __builtin_amdgcn_s_setprio(1);                                                   \
    _Pragma("unroll") for (int m2 = 0; m2 < 2; ++m2)                                 \
      _Pragma("unroll") for (int ks = 0; ks < 2; ++ks)                               \
        _Pragma("unroll") for (int ni = 0; ni < 4; ++ni)                             \
          acc[(q)*2+m2][ni] = __builtin_amdgcn_mfma_f32_16x16x32_bf16(               \
              af[m2][ks], BF[ni][ks], acc[(q)*2+m2][ni], 0, 0, 0);                   \
    __builtin_amdgcn_s_setprio(0);

#define G2_LDA(q)                                                                    \
    _Pragma("unroll") for (int m2 = 0; m2 < 2; ++m2)                                 \
      _Pragma("unroll") for (int ks = 0; ks < 2; ++ks)                               \
        af[m2][ks] = *(const short8*)(Ab + (lds_off(rbA + ((q)*2+m2)*16, ks, lq) ^ X4));

    // phase 0
    #pragma unroll
    for (int ni = 0; ni < 4; ++ni)
      #pragma unroll
      for (int ks = 0; ks < 2; ++ks)
        BF[ni][ks] = *(const short8*)(Bb + (lds_off(wn * 64 + ni * 16 + lrow, ks, lq) ^ X4));
    G2_LDA(0);
    if (t + 1 < NKT) { SA(d ^ 1, 3); SB(d ^ 1, 3); }
    __builtin_amdgcn_s_barrier();
    asm volatile("s_waitcnt lgkmcnt(0)" ::: "memory");
    __builtin_amdgcn_sched_barrier(0);
    G2_MFMA(0);
    __builtin_amdgcn_s_barrier();
    // phase 1
    G2_LDA(1);
    if (t + 2 < NKT) { SA(d, 0); SB(d, 0); }
    __builtin_amdgcn_s_barrier();
    asm volatile("s_waitcnt lgkmcnt(0)" ::: "memory");
    __builtin_amdgcn_sched_barrier(0);
    G2_MFMA(1);
    __builtin_amdgcn_s_barrier();
    // phase 2
    G2_LDA(2);
    if (t + 2 < NKT) { SA(d, 1); SB(d, 1); }
    __builtin_amdgcn_s_barrier();
    asm volatile("s_waitcnt lgkmcnt(0)" ::: "memory");
    __builtin_amdgcn_sched_barrier(0);
    G2_MFMA(2);
    __builtin_amdgcn_s_barrier();
    // phase 3
    G2_LDA(3);
    if (t + 2 < NKT) {
      SA(d, 2); SB(d, 2);
      asm volatile("s_waitcnt vmcnt(6)" ::: "memory");
    } else {
      asm volatile("s_waitcnt vmcnt(0)" ::: "memory");
    }
    __builtin_amdgcn_s_barrier();
    asm volatile("s_waitcnt lgkmcnt(0)" ::: "memory");
    __builtin_amdgcn_sched_barrier(0);
    G2_MFMA(3);
    __builtin_amdgcn_s_barrier();
  }

  // ---- epilogue: LoRA via rank-8 MFMA, direct (row-major) stores
  __syncthreads();
  unsigned short* sLo2 = (unsigned short*)lds;            // [256][32] SCALE*low2
  unsigned short* sB2  = (unsigned short*)(lds + 16384);  // [256][32] Bd rows
  {
    short8 z = {};
    if (tid < 256) {
      const float* lp = low + ((long)e * T_ + mt * 256 + tid) * R_;
      short8 v;
      #pragma unroll
      for (int r = 0; r < 8; ++r) ((unsigned short*)&v)[r] = f2bf(SCALE_ * lp[r]);
      *(short8*)(sLo2 + tid * 32) = v;
      *(short8*)(sLo2 + tid * 32 + 8) = z;
      *(short8*)(sLo2 + tid * 32 + 16) = z;
      *(short8*)(sLo2 + tid * 32 + 24) = z;
    } else {
      int r = tid - 256;
      const float* bp = Bd + ((long)e * H_ + nt * 256 + r) * R_;
      short8 v;
      #pragma unroll
      for (int k = 0; k < 8; ++k) ((unsigned short*)&v)[k] = f2bf(bp[k]);
      *(short8*)(sB2 + r * 32) = v;
      *(short8*)(sB2 + r * 32 + 8) = z;
      *(short8*)(sB2 + r * 32 + 16) = z;
      *(short8*)(sB2 + r * 32 + 24) = z;
    }
  }
  __syncthreads();
  #pragma unroll
  for (int mi = 0; mi < 8; ++mi) {
    short8 alo = *(const short8*)(sLo2 + (rbA + mi * 16) * 32 + lq * 8);
    #pragma unroll
    for (int ni = 0; ni < 4; ++ni) {
      short8 bd2 = *(const short8*)(sB2 + (wn * 64 + ni * 16 + lrow) * 32 + lq * 8);
      acc[mi][ni] = __builtin_amdgcn_mfma_f32_16x16x32_bf16(alo, bd2, acc[mi][ni], 0, 0, 0);
    }
  }
  {
    long rowbase = (long)e * T_ + mt * 256 + wm * 128;
    int colbase = nt * 256 + wn * 64;
    #pragma unroll
    for (int mi = 0; mi < 8; ++mi)
      #pragma unroll
      for (int j = 0; j < 4; ++j) {
        long row = rowbase + mi * 16 + lq * 4 + j;
        #pragma unroll
        for (int ni = 0; ni < 4; ++ni)
          Out[row * H_ + colbase + ni * 16 + lrow] = acc[mi][ni][j];
      }
  }
}

extern "C" void kernel_launch(void* const* d_in, const int* in_sizes, int n_in,
                              void* d_out, int out_size, void* d_ws, size_t ws_size,
                              hipStream_t stream) {
  const float* x   = (const float*)d_in[0];
  const float* Wgu = (const float*)d_in[1];
  const float* Agu = (const float*)d_in[2];
  const float* Bgu = (const float*)d_in[3];
  const float* Wd  = (const float*)d_in[4];
  const float* Ad  = (const float*)d_in[5];
  const float* Bd  = (const float*)d_in[6];
  float* out = (float*)d_out;

  char* ws = (char*)d_ws;
  const size_t SZ_H   = (size_t)E_ * T_ * D_ * 2;        // 128 MiB bf16 h
  const size_t SZ_LOW = (size_t)E_ * T_ * R_ * 4;        // 512 KiB
  const size_t SZ_XB  = (size_t)E_ * T_ * H_ * 2;        // 64 MiB
  const size_t SZ_WGU = (size_t)E_ * TWO_D_ * H_ * 2;    // 256 MiB

  unsigned short* hbuf = (unsigned short*)ws;
  float* low1 = (float*)(ws + SZ_H);
  float* low2 = (float*)(ws + SZ_H + SZ_LOW);
  unsigned short* xb   = (unsigned short*)(ws + SZ_H + 2 * SZ_LOW);
  unsigned short* wgub = (unsigned short*)(ws + SZ_H + 2 * SZ_LOW + SZ_XB);
  unsigned short* wdb  = (unsigned short*)(ws + SZ_H + 2 * SZ_LOW + SZ_XB + SZ_WGU);

  // low1 + x->bf16 (blocks 0..4095) || Wgu->bf16 (blocks 4096..5119)
  hipLaunchKernelGGL(k_pre, dim3(E_ * T_ / 4 + 1024), dim3(256), 0, stream,
                     x, Agu, low1, xb, Wgu, wgub);
  // gemm1 + Wd->bf16 ride
  hipLaunchKernelGGL(k_gemm1_8p, dim3(E_ * (T_ / 256) * (D_ / 128)), dim3(512), 0, stream,
                     xb, wgub, Bgu, low1, hbuf, Wd, wdb);
  hipLaunchKernelGGL(k_low2, dim3(E_ * T_ / 4), dim3(256), 0, stream, hbuf, Ad, low2);
  hipLaunchKernelGGL(k_gemm2_8p, dim3(E_ * (T_ / 256) * (H_ / 256)), dim3(512), 0, stream,
                     hbuf, wdb, Bd, low2, out);
}

// Round 8
// 1124.879 us; speedup vs baseline: 1.1379x; 1.0411x over previous
//
#include <hip/hip_runtime.h>
#include <hip/hip_bf16.h>

#define E_ 8
#define H_ 2048
#define D_ 4096
#define R_ 8
#define T_ 2048
#define TWO_D_ 8192
#define SCALE_ 2.0f

typedef __attribute__((ext_vector_type(8))) short short8;
typedef __attribute__((ext_vector_type(4))) float f32x4;

__device__ __forceinline__ unsigned short f2bf(float f) {
  union { float f; unsigned u; } c; c.f = f;
  unsigned u = c.u + 0x7fffu + ((c.u >> 16) & 1u);  // RNE
  return (unsigned short)(u >> 16);
}
__device__ __forceinline__ float bf2f(unsigned short s) {
  union { unsigned u; float f; } c; c.u = ((unsigned)s) << 16;
  return c.f;
}

// async 16B global -> LDS (linear dest: wave-uniform base + lane*16)
__device__ __forceinline__ void gl16(const void* g, void* l) {
  __builtin_amdgcn_global_load_lds(
      (const __attribute__((address_space(1))) void*)g,
      (__attribute__((address_space(3))) void*)l, 16, 0, 0);
}

// LDS byte offset inside a 32KB operand region laid out [qtr][half][32 rows][64 cols bf16]
__device__ __forceinline__ int lds_off(int rr, int ks, int lq) {
  return (((rr >> 5) & 3) << 13) | (((rr >> 7) & 1) << 12) | ((rr & 31) << 7) | (ks << 6) | (lq << 4);
}

// ---------------- fused pre-pass: low1 = x@Agu^T + x->bf16  ||  Wgu->bf16  ||  Wd->bf16
__global__ __launch_bounds__(256) void k_pre(const float* __restrict__ x,
                                             const float* __restrict__ Agu,
                                             float* __restrict__ low,
                                             unsigned short* __restrict__ xb,
                                             const float* __restrict__ Wgu,
                                             unsigned short* __restrict__ wgub,
                                             const float* __restrict__ Wd,
                                             unsigned short* __restrict__ wdb) {
  const int NB_LOW = E_ * T_ / 4;  // 4096
  if (blockIdx.x < NB_LOW) {
    int wave = (blockIdx.x * 256 + threadIdx.x) >> 6;
    int lane = threadIdx.x & 63;
    int e = wave >> 11;
    const float* Ae = Agu + (long)e * R_ * H_;
    float acc[R_] = {0.f,0.f,0.f,0.f,0.f,0.f,0.f,0.f};
    for (int it = 0; it < H_ / 256; ++it) {
      int i = it * 256 + lane * 4;
      const float* xp = x + (long)wave * H_;
      f32x4 v = *(const f32x4*)(xp + i);
      ushort4 u; u.x=f2bf(v[0]); u.y=f2bf(v[1]); u.z=f2bf(v[2]); u.w=f2bf(v[3]);
      *(ushort4*)(xb + (long)wave * H_ + i) = u;
      #pragma unroll
      for (int r = 0; r < R_; ++r) {
        f32x4 a = *(const f32x4*)(Ae + r * H_ + i);
        acc[r] += v[0]*a[0] + v[1]*a[1] + v[2]*a[2] + v[3]*a[3];
      }
    }
    #pragma unroll
    for (int r = 0; r < R_; ++r) {
      float v = acc[r];
      #pragma unroll
      for (int off = 32; off > 0; off >>= 1) v += __shfl_xor(v, off);
      acc[r] = v;
    }
    if (lane == 0) {
      #pragma unroll
      for (int r = 0; r < R_; ++r) low[(long)wave * R_ + r] = acc[r];
    }
  } else if (blockIdx.x < NB_LOW + 1024) {
    const long n = (long)E_ * TWO_D_ * H_;
    long i = ((long)(blockIdx.x - NB_LOW) * 256 + threadIdx.x) * 8;
    const long stride = (long)1024 * 256 * 8;
    for (; i < n; i += stride) {
      f32x4 a = *(const f32x4*)(Wgu + i);
      f32x4 b = *(const f32x4*)(Wgu + i + 4);
      ushort4 lo, hi;
      lo.x=f2bf(a[0]); lo.y=f2bf(a[1]); lo.z=f2bf(a[2]); lo.w=f2bf(a[3]);
      hi.x=f2bf(b[0]); hi.y=f2bf(b[1]); hi.z=f2bf(b[2]); hi.w=f2bf(b[3]);
      *(ushort4*)(wgub + i) = lo;
      *(ushort4*)(wgub + i + 4) = hi;
    }
  } else {
    const long n = (long)E_ * H_ * D_;
    long i = ((long)(blockIdx.x - NB_LOW - 1024) * 256 + threadIdx.x) * 8;
    const long stride = (long)1024 * 256 * 8;
    for (; i < n; i += stride) {
      f32x4 a = *(const f32x4*)(Wd + i);
      f32x4 b = *(const f32x4*)(Wd + i + 4);
      ushort4 lo, hi;
      lo.x=f2bf(a[0]); lo.y=f2bf(a[1]); lo.z=f2bf(a[2]); lo.w=f2bf(a[3]);
      hi.x=f2bf(b[0]); hi.y=f2bf(b[1]); hi.z=f2bf(b[2]); hi.w=f2bf(b[3]);
      *(ushort4*)(wdb + i) = lo;
      *(ushort4*)(wdb + i + 4) = hi;
    }
  }
}

// ---------------- rank-8 projection from bf16 h (low2)
__global__ __launch_bounds__(256) void k_low2(const unsigned short* __restrict__ Hb,
                                              const float* __restrict__ Ad,
                                              float* __restrict__ low) {
  int wave = (blockIdx.x * 256 + threadIdx.x) >> 6;
  int lane = threadIdx.x & 63;
  int e = wave >> 11;
  const float* Ae = Ad + (long)e * R_ * D_;
  float acc[R_] = {0.f,0.f,0.f,0.f,0.f,0.f,0.f,0.f};
  for (int it = 0; it < D_ / 256; ++it) {
    int i = it * 256 + lane * 4;
    ushort4 u = *(const ushort4*)(Hb + (long)wave * D_ + i);
    float xv[4] = {bf2f(u.x), bf2f(u.y), bf2f(u.z), bf2f(u.w)};
    #pragma unroll
    for (int r = 0; r < R_; ++r) {
      f32x4 a = *(const f32x4*)(Ae + r * D_ + i);
      acc[r] += xv[0]*a[0] + xv[1]*a[1] + xv[2]*a[2] + xv[3]*a[3];
    }
  }
  #pragma unroll
  for (int r = 0; r < R_; ++r) {
    float v = acc[r];
    #pragma unroll
    for (int off = 32; off > 0; off >>= 1) v += __shfl_xor(v, off);
    acc[r] = v;
  }
  if (lane == 0) {
    #pragma unroll
    for (int r = 0; r < R_; ++r) low[(long)wave * R_ + r] = acc[r];
  }
}

// ======================= GEMM1: 256x128(gate)+128(up), BK=64, 8-phase =======================
// h = up*silu(gate); gate_up = x@Wgu^T + SCALE*low1@Bgu^T (LoRA folded as rank-8 MFMA step)
__global__ __launch_bounds__(512, 2) void k_gemm1_8p(
    const unsigned short* __restrict__ Xb, const unsigned short* __restrict__ Wb,
    const float* __restrict__ Bgu, const float* __restrict__ low,
    unsigned short* __restrict__ Hout) {
  __shared__ __align__(16) char lds[131072];  // A: d*32768, B: 65536 + d*32768

  const int MT = T_ / 256, NT = D_ / 128;  // 8, 32
  int b = blockIdx.x;
  int cpx = (int)gridDim.x >> 3;
  int swz = (b & 7) * cpx + (b >> 3);     // bijective: grid % 8 == 0
  int e  = swz / (MT * NT);
  int r0 = swz % (MT * NT);
  int nt = r0 / MT, mt = r0 % MT;

  int tid = threadIdx.x, lane = tid & 63;
  int wid = tid >> 6, wm = wid >> 2, wn = wid & 3;
  int lrow = lane & 15, lq = lane >> 4;
  int X4 = (lrow & 7) << 4;
  const int NKT = H_ / 64;  // 32

  unsigned ro = (unsigned)tid * 16;
  unsigned so = ro ^ (((ro >> 7) & 7u) << 4);
  int sh = (so >> 12) & 1, sr = (so >> 7) & 31, sc = (so & 127) >> 1;
  const unsigned short* pA[4]; const unsigned short* pB[4];
  #pragma unroll
  for (int q = 0; q < 4; ++q) {
    long arow = (long)e * T_ + mt * 256 + sh * 128 + q * 32 + sr;
    pA[q] = Xb + arow * H_ + sc;
    long wrow = sh ? ((long)e * TWO_D_ + D_ + nt * 128 + q * 32 + sr)
                   : ((long)e * TWO_D_ +      nt * 128 + q * 32 + sr);
    pB[q] = Wb + wrow * (long)H_ + sc;
  }
  auto SA = [&](int d, int q) { gl16(pA[q], lds + d * 32768 + q * 8192 + ro); pA[q] += 64; };
  auto SB = [&](int d, int q) { gl16(pB[q], lds + 65536 + d * 32768 + q * 8192 + ro); pB[q] += 64; };

  f32x4 accg[2][8] = {}, accu[2][8] = {};  // [nj][mi]
  short8 BG[2][2], BU[2][2], af[2][2];

  SA(0,0); SB(0,0); SA(0,1); SB(0,1); SA(0,2); SB(0,2); SA(0,3); SB(0,3);
  SA(1,0); SB(1,0); SA(1,1); SB(1,1); SA(1,2); SB(1,2);
  asm volatile("s_waitcnt vmcnt(6)" ::: "memory");
  __builtin_amdgcn_s_barrier();

  int rbA = wm * 128 + lrow;
  for (int t = 0; t < NKT; ++t) {
    int d = t & 1;
    const char* Ab = lds + d * 32768;
    const char* Bb = lds + 65536 + d * 32768;

#define G1_MFMA(q)                                                                   \
    __builtin_amdgcn_s_setprio(1);                                                   \
    _Pragma("unroll") for (int m2 = 0; m2 < 2; ++m2)                                 \
      _Pragma("unroll") for (int ks = 0; ks < 2; ++ks)                               \
        _Pragma("unroll") for (int nj = 0; nj < 2; ++nj) {                           \
          accg[nj][(q)*2+m2] = __builtin_amdgcn_mfma_f32_16x16x32_bf16(              \
              BG[nj][ks], af[m2][ks], accg[nj][(q)*2+m2], 0, 0, 0);                  \
          accu[nj][(q)*2+m2] = __builtin_amdgcn_mfma_f32_16x16x32_bf16(              \
              BU[nj][ks], af[m2][ks], accu[nj][(q)*2+m2], 0, 0, 0);                  \
        }                                                                            \
    __builtin_amdgcn_s_setprio(0);

#define G1_LDA(q)                                                                    \
    _Pragma("unroll") for (int m2 = 0; m2 < 2; ++m2)                                 \
      _Pragma("unroll") for (int ks = 0; ks < 2; ++ks)                               \
        af[m2][ks] = *(const short8*)(Ab + (lds_off(rbA + ((q)*2+m2)*16, ks, lq) ^ X4));

#define G1_SYNC()                                                                    \
    __builtin_amdgcn_s_barrier();                                                    \
    asm volatile("s_waitcnt lgkmcnt(0)" ::: "memory");                               \
    __builtin_amdgcn_sched_barrier(0);

    // phase 0: B-frags + A-quad0; stage tile t+1 last units
    #pragma unroll
    for (int nj = 0; nj < 2; ++nj)
      #pragma unroll
      for (int ks = 0; ks < 2; ++ks) {
        int rg = wn * 32 + nj * 16 + lrow;
        BG[nj][ks] = *(const short8*)(Bb + (lds_off(rg, ks, lq) ^ X4));
        BU[nj][ks] = *(const short8*)(Bb + (lds_off(rg + 128, ks, lq) ^ X4));
      }
    G1_LDA(0);
    if (t + 1 < NKT) { SA(d ^ 1, 3); SB(d ^ 1, 3); }
    G1_SYNC();
    G1_MFMA(0);
    __builtin_amdgcn_s_barrier();
    // phase 1
    G1_LDA(1);
    if (t + 2 < NKT) { SA(d, 0); SB(d, 0); }
    G1_SYNC();
    G1_MFMA(1);
    __builtin_amdgcn_s_barrier();
    // phase 2
    G1_LDA(2);
    if (t + 2 < NKT) { SA(d, 1); SB(d, 1); }
    G1_SYNC();
    G1_MFMA(2);
    __builtin_amdgcn_s_barrier();
    // phase 3 (counted vmcnt: 6 loads of tile t+2 may stay in flight)
    G1_LDA(3);
    if (t + 2 < NKT) {
      SA(d, 2); SB(d, 2);
      asm volatile("s_waitcnt vmcnt(6)" ::: "memory");
    } else {
      asm volatile("s_waitcnt vmcnt(0)" ::: "memory");
    }
    G1_SYNC();
    G1_MFMA(3);
    __builtin_amdgcn_s_barrier();
  }

  // ---- epilogue: fold LoRA via one rank-8 (K=32 zero-padded) MFMA step
  __syncthreads();
  unsigned short* sLo2 = (unsigned short*)lds;            // [256][32] bf16: SCALE*low1
  unsigned short* sB2  = (unsigned short*)(lds + 16384);  // [256][32] bf16: Bgu rows (gate|up)
  {
    short8 z = {};
    if (tid < 256) {
      const float* lp = low + ((long)e * T_ + mt * 256 + tid) * R_;
      short8 v;
      #pragma unroll
      for (int r = 0; r < 8; ++r) ((unsigned short*)&v)[r] = f2bf(SCALE_ * lp[r]);
      *(short8*)(sLo2 + tid * 32) = v;
      *(short8*)(sLo2 + tid * 32 + 8) = z;
      *(short8*)(sLo2 + tid * 32 + 16) = z;
      *(short8*)(sLo2 + tid * 32 + 24) = z;
    } else {
      int r = tid - 256;
      long wrow = (r < 128) ? ((long)e * TWO_D_ + nt * 128 + r)
                            : ((long)e * TWO_D_ + D_ + nt * 128 + (r - 128));
      const float* bp = Bgu + wrow * R_;
      short8 v;
      #pragma unroll
      for (int k = 0; k < 8; ++k) ((unsigned short*)&v)[k] = f2bf(bp[k]);
      *(short8*)(sB2 + r * 32) = v;
      *(short8*)(sB2 + r * 32 + 8) = z;
      *(short8*)(sB2 + r * 32 + 16) = z;
      *(short8*)(sB2 + r * 32 + 24) = z;
    }
  }
  __syncthreads();
  {
    #pragma unroll
    for (int mi = 0; mi < 8; ++mi) {
      short8 alo = *(const short8*)(sLo2 + (rbA + mi * 16) * 32 + lq * 8);
      #pragma unroll
      for (int nj = 0; nj < 2; ++nj) {
        int rg = wn * 32 + nj * 16 + lrow;
        short8 bg2 = *(const short8*)(sB2 + rg * 32 + lq * 8);
        short8 bu2 = *(const short8*)(sB2 + (rg + 128) * 32 + lq * 8);
        accg[nj][mi] = __builtin_amdgcn_mfma_f32_16x16x32_bf16(bg2, alo, accg[nj][mi], 0, 0, 0);
        accu[nj][mi] = __builtin_amdgcn_mfma_f32_16x16x32_bf16(bu2, alo, accu[nj][mi], 0, 0, 0);
      }
    }
  }
  // silu + pack -> sT [256][136], then coalesced store
  unsigned short* sT = (unsigned short*)(lds + 32768);
  #pragma unroll
  for (int mi = 0; mi < 8; ++mi) {
    int tl = rbA + mi * 16;
    #pragma unroll
    for (int nj = 0; nj < 2; ++nj) {
      int cb = wn * 32 + nj * 16 + lq * 4;
      ushort4 o;
      #pragma unroll
      for (int j = 0; j < 4; ++j) {
        float gate = accg[nj][mi][j];
        float up   = accu[nj][mi][j];
        float hh = up * (gate / (1.f + __expf(-gate)));
        (&o.x)[j] = f2bf(hh);
      }
      *(ushort4*)(sT + tl * 136 + cb) = o;
    }
  }
  __syncthreads();
  {
    long base = ((long)e * T_ + mt * 256) * D_ + nt * 128;
    int rr2 = tid >> 4, cc2 = (tid & 15) * 8;
    #pragma unroll
    for (int p = 0; p < 8; ++p) {
      int r = p * 32 + rr2;
      short8 v = *(const short8*)(sT + r * 136 + cc2);
      *(short8*)(Hout + base + (long)r * D_ + cc2) = v;
    }
  }
}

// ======================= GEMM2: 256x256, BK=64, 8-phase =======================
// out = h@Wd^T + SCALE*low2@Bd^T (fp32 out; LoRA folded as rank-8 MFMA step)
__global__ __launch_bounds__(512, 2) void k_gemm2_8p(
    const unsigned short* __restrict__ Hin, const unsigned short* __restrict__ Wdb,
    const float* __restrict__ Bd, const float* __restrict__ low,
    float* __restrict__ Out) {
  __shared__ __align__(16) char lds[131072];

  const int MT = T_ / 256, NT = H_ / 256;  // 8, 8
  int b = blockIdx.x;
  int cpx = (int)gridDim.x >> 3;
  int swz = (b & 7) * cpx + (b >> 3);
  int e  = swz / (MT * NT);
  int r0 = swz % (MT * NT);
  int nt = r0 / MT, mt = r0 % MT;

  int tid = threadIdx.x, lane = tid & 63;
  int wid = tid >> 6, wm = wid >> 2, wn = wid & 3;
  int lrow = lane & 15, lq = lane >> 4;
  int X4 = (lrow & 7) << 4;
  const int NKT = D_ / 64;  // 64

  unsigned ro = (unsigned)tid * 16;
  unsigned so = ro ^ (((ro >> 7) & 7u) << 4);
  int sh = (so >> 12) & 1, sr = (so >> 7) & 31, sc = (so & 127) >> 1;
  const unsigned short* pA[4]; const unsigned short* pB[4];
  #pragma unroll
  for (int q = 0; q < 4; ++q) {
    long arow = (long)e * T_ + mt * 256 + sh * 128 + q * 32 + sr;
    pA[q] = Hin + arow * D_ + sc;
    long wrow = (long)e * H_ + nt * 256 + sh * 128 + q * 32 + sr;
    pB[q] = Wdb + wrow * (long)D_ + sc;
  }
  auto SA = [&](int d, int q) { gl16(pA[q], lds + d * 32768 + q * 8192 + ro); pA[q] += 64; };
  auto SB = [&](int d, int q) { gl16(pB[q], lds + 65536 + d * 32768 + q * 8192 + ro); pB[q] += 64; };

  f32x4 acc[8][4] = {};  // [mi][ni]
  short8 BF[4][2], af[2][2];

  SA(0,0); SB(0,0); SA(0,1); SB(0,1); SA(0,2); SB(0,2); SA(0,3); SB(0,3);
  SA(1,0); SB(1,0); SA(1,1); SB(1,1); SA(1,2); SB(1,2);
  asm volatile("s_waitcnt vmcnt(6)" ::: "memory");
  __builtin_amdgcn_s_barrier();

  int rbA = wm * 128 + lrow;
  for (int t = 0; t < NKT; ++t) {
    int d = t & 1;
    const char* Ab = lds + d * 32768;
    const char* Bb = lds + 65536 + d * 32768;

#define G2_MFMA(q)                                                                   \
    __builtin_amdgcn_s_setprio(1);                                                   \
    _Pragma("unroll") for (int m2 = 0; m2 < 2; ++m2)                                 \
      _Pragma("unroll") for (int ks = 0; ks < 2; ++ks)                               \
        _Pragma("unroll") for (int ni = 0; ni < 4; ++ni)                             \
          acc[(q)*2+m2][ni] = __builtin_amdgcn_mfma_f32_16x16x32_bf16(               \
              af[m2][ks], BF[ni][ks], acc[(q)*2+m2][ni], 0, 0, 0);                   \
    __builtin_amdgcn_s_setprio(0);

#define G2_LDA(q)                                                                    \
    _Pragma("unroll") for (int m2 = 0; m2 < 2; ++m2)                                 \
      _Pragma("unroll") for (int ks = 0; ks < 2; ++ks)                               \
        af[m2][ks] = *(const short8*)(Ab + (lds_off(rbA + ((q)*2+m2)*16, ks, lq) ^ X4));

    // phase 0
    #pragma unroll
    for (int ni = 0; ni < 4; ++ni)
      #pragma unroll
      for (int ks = 0; ks < 2; ++ks)
        BF[ni][ks] = *(const short8*)(Bb + (lds_off(wn * 64 + ni * 16 + lrow, ks, lq) ^ X4));
    G2_LDA(0);
    if (t + 1 < NKT) { SA(d ^ 1, 3); SB(d ^ 1, 3); }
    __builtin_amdgcn_s_barrier();
    asm volatile("s_waitcnt lgkmcnt(0)" ::: "memory");
    __builtin_amdgcn_sched_barrier(0);
    G2_MFMA(0);
    __builtin_amdgcn_s_barrier();
    // phase 1
    G2_LDA(1);
    if (t + 2 < NKT) { SA(d, 0); SB(d, 0); }
    __builtin_amdgcn_s_barrier();
    asm volatile("s_waitcnt lgkmcnt(0)" ::: "memory");
    __builtin_amdgcn_sched_barrier(0);
    G2_MFMA(1);
    __builtin_amdgcn_s_barrier();
    // phase 2
    G2_LDA(2);
    if (t + 2 < NKT) { SA(d, 1); SB(d, 1); }
    __builtin_amdgcn_s_barrier();
    asm volatile("s_waitcnt lgkmcnt(0)" ::: "memory");
    __builtin_amdgcn_sched_barrier(0);
    G2_MFMA(2);
    __builtin_amdgcn_s_barrier();
    // phase 3
    G2_LDA(3);
    if (t + 2 < NKT) {
      SA(d, 2); SB(d, 2);
      asm volatile("s_waitcnt vmcnt(6)" ::: "memory");
    } else {
      asm volatile("s_waitcnt vmcnt(0)" ::: "memory");
    }
    __builtin_amdgcn_s_barrier();
    asm volatile("s_waitcnt lgkmcnt(0)" ::: "memory");
    __builtin_amdgcn_sched_barrier(0);
    G2_MFMA(3);
    __builtin_amdgcn_s_barrier();
  }

  // ---- epilogue: LoRA via rank-8 MFMA, direct (row-major) stores
  __syncthreads();
  unsigned short* sLo2 = (unsigned short*)lds;            // [256][32] SCALE*low2
  unsigned short* sB2  = (unsigned short*)(lds + 16384);  // [256][32] Bd rows
  {
    short8 z = {};
    if (tid < 256) {
      const float* lp = low + ((long)e * T_ + mt * 256 + tid) * R_;
      short8 v;
      #pragma unroll
      for (int r = 0; r < 8; ++r) ((unsigned short*)&v)[r] = f2bf(SCALE_ * lp[r]);
      *(short8*)(sLo2 + tid * 32) = v;
      *(short8*)(sLo2 + tid * 32 + 8) = z;
      *(short8*)(sLo2 + tid * 32 + 16) = z;
      *(short8*)(sLo2 + tid * 32 + 24) = z;
    } else {
      int r = tid - 256;
      const float* bp = Bd + ((long)e * H_ + nt * 256 + r) * R_;
      short8 v;
      #pragma unroll
      for (int k = 0; k < 8; ++k) ((unsigned short*)&v)[k] = f2bf(bp[k]);
      *(short8*)(sB2 + r * 32) = v;
      *(short8*)(sB2 + r * 32 + 8) = z;
      *(short8*)(sB2 + r * 32 + 16) = z;
      *(short8*)(sB2 + r * 32 + 24) = z;
    }
  }
  __syncthreads();
  #pragma unroll
  for (int mi = 0; mi < 8; ++mi) {
    short8 alo = *(const short8*)(sLo2 + (rbA + mi * 16) * 32 + lq * 8);
    #pragma unroll
    for (int ni = 0; ni < 4; ++ni) {
      short8 bd2 = *(const short8*)(sB2 + (wn * 64 + ni * 16 + lrow) * 32 + lq * 8);
      acc[mi][ni] = __builtin_amdgcn_mfma_f32_16x16x32_bf16(alo, bd2, acc[mi][ni], 0, 0, 0);
    }
  }
  {
    long rowbase = (long)e * T_ + mt * 256 + wm * 128;
    int colbase = nt * 256 + wn * 64;
    #pragma unroll
    for (int mi = 0; mi < 8; ++mi)
      #pragma unroll
      for (int j = 0; j < 4; ++j) {
        long row = rowbase + mi * 16 + lq * 4 + j;
        #pragma unroll
        for (int ni = 0; ni < 4; ++ni)
          Out[row * H_ + colbase + ni * 16 + lrow] = acc[mi][ni][j];
      }
  }
}

extern "C" void kernel_launch(void* const* d_in, const int* in_sizes, int n_in,
                              void* d_out, int out_size, void* d_ws, size_t ws_size,
                              hipStream_t stream) {
  const float* x   = (const float*)d_in[0];
  const float* Wgu = (const float*)d_in[1];
  const float* Agu = (const float*)d_in[2];
  const float* Bgu = (const float*)d_in[3];
  const float* Wd  = (const float*)d_in[4];
  const float* Ad  = (const float*)d_in[5];
  const float* Bd  = (const float*)d_in[6];
  float* out = (float*)d_out;

  char* ws = (char*)d_ws;
  const size_t SZ_H   = (size_t)E_ * T_ * D_ * 2;        // 128 MiB bf16 h
  const size_t SZ_LOW = (size_t)E_ * T_ * R_ * 4;        // 512 KiB
  const size_t SZ_XB  = (size_t)E_ * T_ * H_ * 2;        // 64 MiB
  const size_t SZ_WGU = (size_t)E_ * TWO_D_ * H_ * 2;    // 256 MiB

  unsigned short* hbuf = (unsigned short*)ws;
  float* low1 = (float*)(ws + SZ_H);
  float* low2 = (float*)(ws + SZ_H + SZ_LOW);
  unsigned short* xb   = (unsigned short*)(ws + SZ_H + 2 * SZ_LOW);
  unsigned short* wgub = (unsigned short*)(ws + SZ_H + 2 * SZ_LOW + SZ_XB);
  unsigned short* wdb  = (unsigned short*)(ws + SZ_H + 2 * SZ_LOW + SZ_XB + SZ_WGU);

  // low1 + x->bf16 (blocks 0..4095) || Wgu->bf16 (1024 blocks) || Wd->bf16 (1024 blocks)
  hipLaunchKernelGGL(k_pre, dim3(E_ * T_ / 4 + 2048), dim3(256), 0, stream,
                     x, Agu, low1, xb, Wgu, wgub, Wd, wdb);
  hipLaunchKernelGGL(k_gemm1_8p, dim3(E_ * (T_ / 256) * (D_ / 128)), dim3(512), 0, stream,
                     xb, wgub, Bgu, low1, hbuf);
  hipLaunchKernelGGL(k_low2, dim3(E_ * T_ / 4), dim3(256), 0, stream, hbuf, Ad, low2);
  hipLaunchKernelGGL(k_gemm2_8p, dim3(E_ * (T_ / 256) * (H_ / 256)), dim3(512), 0, stream,
                     hbuf, wdb, Bd, low2, out);
}